// Round 5
// baseline (215.586 us; speedup 1.0000x reference)
//
#include <hip/hip_runtime.h>
#include <hip/hip_cooperative_groups.h>
#include <math.h>

namespace cg = cooperative_groups;

#define IMGS 48
#define BLOCKS_PER_IMG 16
#define GRID_BLOCKS (IMGS * BLOCKS_PER_IMG)   // 768 = 3 blocks/CU on 256 CUs
#define F4_PER_THREAD 16                       // 256 thr * 16 f4 * 16 blk = 262144 floats/img

// ---------------- single-pass cooperative kernel ----------------
// x is read ONCE (held in registers across grid.sync). Cross-block partial
// min/max go through device-scope atomic RMWs (atomicExch write, atomicAdd+0
// read) so they are coherent across XCDs — plain loads/stores are NOT (G16).
__global__ __launch_bounds__(256, 3) void lbq_onepass(const float* __restrict__ x,
                                                      const float* __restrict__ rp,
                                                      float* __restrict__ out,
                                                      float* pmin,
                                                      float* pmax) {
    int blk  = blockIdx.x;
    int img  = blk >> 4;                 // 16 blocks per image
    int b    = blk & 15;
    int t    = threadIdx.x;
    int lane = t & 63;
    int wave = t >> 6;

    // ---- phase 1: load 16 float4 (kept live in VGPRs) and reduce ----
    size_t base = (size_t)img * 65536 + (size_t)b * 4096 + t;   // float4 units
    const float4* xin = (const float4*)x + base;
    float4 d[F4_PER_THREAD];
#pragma unroll
    for (int k = 0; k < F4_PER_THREAD; ++k) d[k] = xin[k * 256];

    float mn = INFINITY, mx = -INFINITY;
#pragma unroll
    for (int k = 0; k < F4_PER_THREAD; ++k) {
        mn = fminf(mn, fminf(fminf(d[k].x, d[k].y), fminf(d[k].z, d[k].w)));
        mx = fmaxf(mx, fmaxf(fmaxf(d[k].x, d[k].y), fmaxf(d[k].z, d[k].w)));
    }
#pragma unroll
    for (int off = 32; off >= 1; off >>= 1) {
        mn = fminf(mn, __shfl_xor(mn, off));
        mx = fmaxf(mx, __shfl_xor(mx, off));
    }
    __shared__ float smn[4], smx[4];
    if (lane == 0) { smn[wave] = mn; smx[wave] = mx; }
    __syncthreads();
    if (t == 0) {
        // device-scope RMW -> lands at the cross-XCD coherence point
        atomicExch(&pmin[blk], fminf(fminf(smn[0], smn[1]), fminf(smn[2], smn[3])));
        atomicExch(&pmax[blk], fmaxf(fmaxf(smx[0], smx[1]), fmaxf(smx[2], smx[3])));
    }

    cg::this_grid().sync();

    // ---- phase 2: wave 0 builds the 31-float table ----
    __shared__ float sorted[17];
    __shared__ float s_sb[15], s_vv[16];
    if (wave == 0) {
        // coherent read of the 16 partials (4-way replicated across the wave)
        float pmn = atomicAdd(&pmin[img * 16 + (lane & 15)], 0.0f);
        float pmx = atomicAdd(&pmax[img * 16 + (lane & 15)], 0.0f);
#pragma unroll
        for (int off = 8; off >= 1; off >>= 1) {
            pmn = fminf(pmn, __shfl_xor(pmn, off));
            pmx = fmaxf(pmx, __shfl_xor(pmx, off));
        }
        float m0 = pmn, M0 = pmx;                 // image min / max (all lanes)
        float maxeps = __fadd_rn(M0, 1e-6f);

        // boundary per lane: lane0=min, lanes1..15=split[lane-1], lane16=max+1e-6
        float u = (lane >= 1 && lane <= 15) ? rp[img * 15 + (lane - 1)] : 0.0f;
        // split = u*(max-min)+min, explicit mul-then-add (match XLA, no FMA)
        float split = __fadd_rn(__fmul_rn(u, __fsub_rn(M0, m0)), m0);
        float bval  = (lane == 0) ? m0 : (lane == 16 ? maxeps : split);

        // stable rank among lanes 0..16 (unique; ties broken by lane index)
        int rank = 0;
#pragma unroll
        for (int i = 0; i < 17; ++i) {
            float vi = __shfl(bval, i);
            rank += (vi < bval) || (vi == bval && i < lane);
        }
        if (lane < 17) sorted[rank] = bval;       // intra-wave dep via waitcnt

        // gap g covers [sorted[g], sorted[g+1]); membership constant in a gap
        // -> evaluate first-matching original region (argmax) at tg=sorted[g].
        float tg = sorted[lane & 15];
        float v  = __shfl(bval, 0);               // = min (no-match default)
        bool found = false;
#pragma unroll
        for (int r = 0; r < 16; ++r) {
            float Lr = __shfl(bval, r);           // L[0]=min, L[r]=split[r-1]
            float Rr = __shfl(bval, r + 1);       // R[r]=L[r+1], R[15]=maxeps
            bool c = (tg >= Lr) && (tg < Rr);
            v = (c && !found) ? Lr : v;
            found = found || c;
        }
        if (lane < 16)  s_vv[lane] = v;
        if (lane < 15)  s_sb[lane] = sorted[lane + 1];   // thresholds SB[1..15]
    }
    __syncthreads();

    float sb[15], vv[16];
#pragma unroll
    for (int k = 0; k < 15; ++k) sb[k] = s_sb[k];
#pragma unroll
    for (int k = 0; k < 16; ++k) vv[k] = s_vv[k];

    float4* oput = (float4*)out + base;
#pragma unroll
    for (int k = 0; k < F4_PER_THREAD; ++k) {
        float4 e = d[k];
        float ox = vv[0], oy = vv[0], oz = vv[0], ow = vv[0];
#pragma unroll
        for (int j = 1; j < 16; ++j) {
            ox = (e.x >= sb[j - 1]) ? vv[j] : ox;
            oy = (e.y >= sb[j - 1]) ? vv[j] : oy;
            oz = (e.z >= sb[j - 1]) ? vv[j] : oz;
            ow = (e.w >= sb[j - 1]) ? vv[j] : ow;
        }
        oput[k * 256] = make_float4(ox, oy, oz, ow);
    }
}

// ---------------- fallback: known-good R3 two-kernel pipeline ----------------
__global__ __launch_bounds__(256) void minmax_kernel(const float* __restrict__ x,
                                                     float* __restrict__ pmin,
                                                     float* __restrict__ pmax) {
    int blk = blockIdx.x;            // 0..3071
    int img = blk >> 6;
    int b   = blk & 63;
    const float4* xin = (const float4*)x + (size_t)img * 65536 + (size_t)b * 1024;
    int t = threadIdx.x;

    float mn = INFINITY, mx = -INFINITY;
#pragma unroll
    for (int k = 0; k < 4; ++k) {
        float4 d = xin[k * 256 + t];
        mn = fminf(mn, fminf(fminf(d.x, d.y), fminf(d.z, d.w)));
        mx = fmaxf(mx, fmaxf(fmaxf(d.x, d.y), fmaxf(d.z, d.w)));
    }
#pragma unroll
    for (int off = 32; off >= 1; off >>= 1) {
        mn = fminf(mn, __shfl_xor(mn, off));
        mx = fmaxf(mx, __shfl_xor(mx, off));
    }
    __shared__ float smn[4], smx[4];
    int wave = t >> 6;
    if ((t & 63) == 0) { smn[wave] = mn; smx[wave] = mx; }
    __syncthreads();
    if (t == 0) {
        pmin[blk] = fminf(fminf(smn[0], smn[1]), fminf(smn[2], smn[3]));
        pmax[blk] = fmaxf(fmaxf(smx[0], smx[1]), fmaxf(smx[2], smx[3]));
    }
}

__global__ __launch_bounds__(256) void quant_fused(const float* __restrict__ x,
                                                   const float* __restrict__ pmin,
                                                   const float* __restrict__ pmax,
                                                   const float* __restrict__ rp,
                                                   float* __restrict__ out) {
    int blk  = blockIdx.x;
    int img  = blk >> 6;                 // 64 blocks/image
    int b    = blk & 63;
    int t    = threadIdx.x;
    int lane = t & 63;
    int wave = t >> 6;

    __shared__ float sorted[17];
    __shared__ float s_sb[15], s_vv[16];

    size_t base = (size_t)img * 65536 + (size_t)b * 1024 + t;
    const float4* xin = (const float4*)x + base;
    float4 d0 = xin[0];
    float4 d1 = xin[256];
    float4 d2 = xin[512];
    float4 d3 = xin[768];

    if (wave == 0) {
        float mn = pmin[img * 64 + lane];
        float mx = pmax[img * 64 + lane];
#pragma unroll
        for (int off = 32; off >= 1; off >>= 1) {
            mn = fminf(mn, __shfl_xor(mn, off));
            mx = fmaxf(mx, __shfl_xor(mx, off));
        }
        float maxeps = __fadd_rn(mx, 1e-6f);
        float u = (lane >= 1 && lane <= 15) ? rp[img * 15 + (lane - 1)] : 0.0f;
        float split = __fadd_rn(__fmul_rn(u, __fsub_rn(mx, mn)), mn);
        float bval  = (lane == 0) ? mn : (lane == 16 ? maxeps : split);

        int rank = 0;
#pragma unroll
        for (int i = 0; i < 17; ++i) {
            float vi = __shfl(bval, i);
            rank += (vi < bval) || (vi == bval && i < lane);
        }
        if (lane < 17) sorted[rank] = bval;

        float tg = sorted[lane & 15];
        float v  = __shfl(bval, 0);
        bool found = false;
#pragma unroll
        for (int r = 0; r < 16; ++r) {
            float Lr = __shfl(bval, r);
            float Rr = __shfl(bval, r + 1);
            bool c = (tg >= Lr) && (tg < Rr);
            v = (c && !found) ? Lr : v;
            found = found || c;
        }
        if (lane < 16)  s_vv[lane] = v;
        if (lane < 15)  s_sb[lane] = sorted[lane + 1];
    }
    __syncthreads();

    float sb[15], vv[16];
#pragma unroll
    for (int k = 0; k < 15; ++k) sb[k] = s_sb[k];
#pragma unroll
    for (int k = 0; k < 16; ++k) vv[k] = s_vv[k];

    float4* oput = (float4*)out + base;
    float4 din[4] = {d0, d1, d2, d3};
#pragma unroll
    for (int k = 0; k < 4; ++k) {
        float4 d = din[k];
        float ox = vv[0], oy = vv[0], oz = vv[0], ow = vv[0];
#pragma unroll
        for (int j = 1; j < 16; ++j) {
            ox = (d.x >= sb[j - 1]) ? vv[j] : ox;
            oy = (d.y >= sb[j - 1]) ? vv[j] : oy;
            oz = (d.z >= sb[j - 1]) ? vv[j] : oz;
            ow = (d.w >= sb[j - 1]) ? vv[j] : ow;
        }
        oput[k * 256] = make_float4(ox, oy, oz, ow);
    }
}

extern "C" void kernel_launch(void* const* d_in, const int* in_sizes, int n_in,
                              void* d_out, int out_size, void* d_ws, size_t ws_size,
                              hipStream_t stream) {
    const float* x  = (const float*)d_in[0];
    const float* rp = (const float*)d_in[1];
    float* out  = (float*)d_out;
    float* ws   = (float*)d_ws;
    float* pmin = ws;                    // coop: 768 slots | fallback: 3072
    float* pmax = ws + 4096;             // disjoint in both modes

    void* args[] = {(void*)&x, (void*)&rp, (void*)&out, (void*)&pmin, (void*)&pmax};
    hipError_t err = hipLaunchCooperativeKernel((const void*)lbq_onepass,
                                                dim3(GRID_BLOCKS), dim3(256),
                                                args, 0, stream);
    if (err != hipSuccess) {
        // deterministic fallback: known-good two-kernel pipeline (R3)
        minmax_kernel<<<IMGS * 64, 256, 0, stream>>>(x, pmin, pmax);
        quant_fused<<<IMGS * 64, 256, 0, stream>>>(x, pmin, pmax, rp, out);
    }
}

// Round 8
// 214.917 us; speedup vs baseline: 1.0031x; 1.0031x over previous
//
#include <hip/hip_runtime.h>
#include <hip/hip_cooperative_groups.h>
#include <math.h>

namespace cg = cooperative_groups;

#define IMGS 48
#define BLOCKS_PER_IMG 16
#define GRID_BLOCKS (IMGS * BLOCKS_PER_IMG)   // 768 = 3 blocks/CU on 256 CUs
#define F4_PER_THREAD 16                       // 256 thr * 16 f4 * 16 blk = 262144 floats/img

__device__ __forceinline__ float vmin4(float4 a) {
    return fminf(fminf(a.x, a.y), fminf(a.z, a.w));
}
__device__ __forceinline__ float vmax4(float4 a) {
    return fmaxf(fmaxf(a.x, a.y), fmaxf(a.z, a.w));
}

// ---------------- single-pass cooperative kernel ----------------
// Phase 1: STREAMING min/max over this block's tile (nothing held in regs —
// R5 showed holding 16 float4 across grid.sync() spills to scratch: VGPR=52,
// 123 us). Phase 2: wave 0 builds the 31-float table, then all waves RE-READ
// the same tile (L2/L3-warm: R5's FETCH showed x is ~50% L3-served) and
// quantize. Cross-block partials via device-scope atomic RMWs (XCD-coherent).
__global__ __launch_bounds__(256, 4) void lbq_onepass(const float* __restrict__ x,
                                                      const float* __restrict__ rp,
                                                      float* __restrict__ out,
                                                      float* pmin,
                                                      float* pmax) {
    int blk  = blockIdx.x;
    int img  = blk >> 4;                 // 16 blocks per image
    int b    = blk & 15;
    int t    = threadIdx.x;
    int lane = t & 63;
    int wave = t >> 6;

    size_t base = (size_t)img * 65536 + (size_t)b * 4096 + t;   // float4 units
    const float4* xin = (const float4*)x + base;

    // ---- phase 1: streaming reduce, tree-shaped (short dep chains) ----
    float mn = INFINITY, mx = -INFINITY;
#pragma unroll
    for (int c = 0; c < F4_PER_THREAD / 4; ++c) {
        float4 a0 = xin[(c * 4 + 0) * 256];
        float4 a1 = xin[(c * 4 + 1) * 256];
        float4 a2 = xin[(c * 4 + 2) * 256];
        float4 a3 = xin[(c * 4 + 3) * 256];
        float n0 = fminf(vmin4(a0), vmin4(a1));
        float n1 = fminf(vmin4(a2), vmin4(a3));
        float x0 = fmaxf(vmax4(a0), vmax4(a1));
        float x1 = fmaxf(vmax4(a2), vmax4(a3));
        mn = fminf(mn, fminf(n0, n1));
        mx = fmaxf(mx, fmaxf(x0, x1));
    }
#pragma unroll
    for (int off = 32; off >= 1; off >>= 1) {
        mn = fminf(mn, __shfl_xor(mn, off));
        mx = fmaxf(mx, __shfl_xor(mx, off));
    }
    __shared__ float smn[4], smx[4];
    if (lane == 0) { smn[wave] = mn; smx[wave] = mx; }
    __syncthreads();
    if (t == 0) {
        // device-scope RMW -> lands at the cross-XCD coherence point
        atomicExch(&pmin[blk], fminf(fminf(smn[0], smn[1]), fminf(smn[2], smn[3])));
        atomicExch(&pmax[blk], fmaxf(fmaxf(smx[0], smx[1]), fmaxf(smx[2], smx[3])));
    }

    cg::this_grid().sync();

    // ---- phase 2a: wave 0 builds the 31-float table ----
    __shared__ float sorted[17];
    __shared__ float s_sb[15], s_vv[16];
    if (wave == 0) {
        // coherent read of the 16 partials (4-way replicated across the wave)
        float pmn = atomicAdd(&pmin[img * 16 + (lane & 15)], 0.0f);
        float pmx = atomicAdd(&pmax[img * 16 + (lane & 15)], 0.0f);
#pragma unroll
        for (int off = 8; off >= 1; off >>= 1) {
            pmn = fminf(pmn, __shfl_xor(pmn, off));
            pmx = fmaxf(pmx, __shfl_xor(pmx, off));
        }
        float m0 = pmn, M0 = pmx;                 // image min / max (all lanes)
        float maxeps = __fadd_rn(M0, 1e-6f);

        // boundary per lane: lane0=min, lanes1..15=split[lane-1], lane16=max+1e-6
        float u = (lane >= 1 && lane <= 15) ? rp[img * 15 + (lane - 1)] : 0.0f;
        // split = u*(max-min)+min, explicit mul-then-add (match XLA, no FMA)
        float split = __fadd_rn(__fmul_rn(u, __fsub_rn(M0, m0)), m0);
        float bval  = (lane == 0) ? m0 : (lane == 16 ? maxeps : split);

        // stable rank among lanes 0..16 (unique; ties broken by lane index)
        int rank = 0;
#pragma unroll
        for (int i = 0; i < 17; ++i) {
            float vi = __shfl(bval, i);
            rank += (vi < bval) || (vi == bval && i < lane);
        }
        if (lane < 17) sorted[rank] = bval;       // intra-wave dep via waitcnt

        // gap g covers [sorted[g], sorted[g+1]); membership constant in a gap
        // -> evaluate first-matching original region (argmax) at tg=sorted[g].
        float tg = sorted[lane & 15];
        float v  = __shfl(bval, 0);               // = min (no-match default)
        bool found = false;
#pragma unroll
        for (int r = 0; r < 16; ++r) {
            float Lr = __shfl(bval, r);           // L[0]=min, L[r]=split[r-1]
            float Rr = __shfl(bval, r + 1);       // R[r]=L[r+1], R[15]=maxeps
            bool c = (tg >= Lr) && (tg < Rr);
            v = (c && !found) ? Lr : v;
            found = found || c;
        }
        if (lane < 16)  s_vv[lane] = v;
        if (lane < 15)  s_sb[lane] = sorted[lane + 1];   // thresholds SB[1..15]
    }
    __syncthreads();

    float sb[15], vv[16];
#pragma unroll
    for (int k = 0; k < 15; ++k) sb[k] = s_sb[k];
#pragma unroll
    for (int k = 0; k < 16; ++k) vv[k] = s_vv[k];

    // ---- phase 2b: re-read tile (cache-warm) and quantize ----
    float4* oput = (float4*)out + base;
#pragma unroll
    for (int c = 0; c < F4_PER_THREAD / 4; ++c) {
        float4 e0 = xin[(c * 4 + 0) * 256];
        float4 e1 = xin[(c * 4 + 1) * 256];
        float4 e2 = xin[(c * 4 + 2) * 256];
        float4 e3 = xin[(c * 4 + 3) * 256];
        float4 r0 = make_float4(vv[0], vv[0], vv[0], vv[0]);
        float4 r1 = r0, r2 = r0, r3 = r0;
#pragma unroll
        for (int j = 1; j < 16; ++j) {
            float s = sb[j - 1], w = vv[j];
            r0.x = (e0.x >= s) ? w : r0.x;  r0.y = (e0.y >= s) ? w : r0.y;
            r0.z = (e0.z >= s) ? w : r0.z;  r0.w = (e0.w >= s) ? w : r0.w;
            r1.x = (e1.x >= s) ? w : r1.x;  r1.y = (e1.y >= s) ? w : r1.y;
            r1.z = (e1.z >= s) ? w : r1.z;  r1.w = (e1.w >= s) ? w : r1.w;
            r2.x = (e2.x >= s) ? w : r2.x;  r2.y = (e2.y >= s) ? w : r2.y;
            r2.z = (e2.z >= s) ? w : r2.z;  r2.w = (e2.w >= s) ? w : r2.w;
            r3.x = (e3.x >= s) ? w : r3.x;  r3.y = (e3.y >= s) ? w : r3.y;
            r3.z = (e3.z >= s) ? w : r3.z;  r3.w = (e3.w >= s) ? w : r3.w;
        }
        oput[(c * 4 + 0) * 256] = r0;
        oput[(c * 4 + 1) * 256] = r1;
        oput[(c * 4 + 2) * 256] = r2;
        oput[(c * 4 + 3) * 256] = r3;
    }
}

// ---------------- fallback: known-good R3 two-kernel pipeline ----------------
__global__ __launch_bounds__(256) void minmax_kernel(const float* __restrict__ x,
                                                     float* __restrict__ pmin,
                                                     float* __restrict__ pmax) {
    int blk = blockIdx.x;            // 0..3071
    int img = blk >> 6;
    int b   = blk & 63;
    const float4* xin = (const float4*)x + (size_t)img * 65536 + (size_t)b * 1024;
    int t = threadIdx.x;

    float mn = INFINITY, mx = -INFINITY;
#pragma unroll
    for (int k = 0; k < 4; ++k) {
        float4 d = xin[k * 256 + t];
        mn = fminf(mn, vmin4(d));
        mx = fmaxf(mx, vmax4(d));
    }
#pragma unroll
    for (int off = 32; off >= 1; off >>= 1) {
        mn = fminf(mn, __shfl_xor(mn, off));
        mx = fmaxf(mx, __shfl_xor(mx, off));
    }
    __shared__ float smn[4], smx[4];
    int wave = t >> 6;
    if ((t & 63) == 0) { smn[wave] = mn; smx[wave] = mx; }
    __syncthreads();
    if (t == 0) {
        pmin[blk] = fminf(fminf(smn[0], smn[1]), fminf(smn[2], smn[3]));
        pmax[blk] = fmaxf(fmaxf(smx[0], smx[1]), fmaxf(smx[2], smx[3]));
    }
}

__global__ __launch_bounds__(256) void quant_fused(const float* __restrict__ x,
                                                   const float* __restrict__ pmin,
                                                   const float* __restrict__ pmax,
                                                   const float* __restrict__ rp,
                                                   float* __restrict__ out) {
    int blk  = blockIdx.x;
    int img  = blk >> 6;                 // 64 blocks/image
    int b    = blk & 63;
    int t    = threadIdx.x;
    int lane = t & 63;
    int wave = t >> 6;

    __shared__ float sorted[17];
    __shared__ float s_sb[15], s_vv[16];

    size_t base = (size_t)img * 65536 + (size_t)b * 1024 + t;
    const float4* xin = (const float4*)x + base;
    float4 d0 = xin[0];
    float4 d1 = xin[256];
    float4 d2 = xin[512];
    float4 d3 = xin[768];

    if (wave == 0) {
        float mn = pmin[img * 64 + lane];
        float mx = pmax[img * 64 + lane];
#pragma unroll
        for (int off = 32; off >= 1; off >>= 1) {
            mn = fminf(mn, __shfl_xor(mn, off));
            mx = fmaxf(mx, __shfl_xor(mx, off));
        }
        float maxeps = __fadd_rn(mx, 1e-6f);
        float u = (lane >= 1 && lane <= 15) ? rp[img * 15 + (lane - 1)] : 0.0f;
        float split = __fadd_rn(__fmul_rn(u, __fsub_rn(mx, mn)), mn);
        float bval  = (lane == 0) ? mn : (lane == 16 ? maxeps : split);

        int rank = 0;
#pragma unroll
        for (int i = 0; i < 17; ++i) {
            float vi = __shfl(bval, i);
            rank += (vi < bval) || (vi == bval && i < lane);
        }
        if (lane < 17) sorted[rank] = bval;

        float tg = sorted[lane & 15];
        float v  = __shfl(bval, 0);
        bool found = false;
#pragma unroll
        for (int r = 0; r < 16; ++r) {
            float Lr = __shfl(bval, r);
            float Rr = __shfl(bval, r + 1);
            bool c = (tg >= Lr) && (tg < Rr);
            v = (c && !found) ? Lr : v;
            found = found || c;
        }
        if (lane < 16)  s_vv[lane] = v;
        if (lane < 15)  s_sb[lane] = sorted[lane + 1];
    }
    __syncthreads();

    float sb[15], vv[16];
#pragma unroll
    for (int k = 0; k < 15; ++k) sb[k] = s_sb[k];
#pragma unroll
    for (int k = 0; k < 16; ++k) vv[k] = s_vv[k];

    float4* oput = (float4*)out + base;
    float4 din[4] = {d0, d1, d2, d3};
#pragma unroll
    for (int k = 0; k < 4; ++k) {
        float4 d = din[k];
        float ox = vv[0], oy = vv[0], oz = vv[0], ow = vv[0];
#pragma unroll
        for (int j = 1; j < 16; ++j) {
            ox = (d.x >= sb[j - 1]) ? vv[j] : ox;
            oy = (d.y >= sb[j - 1]) ? vv[j] : oy;
            oz = (d.z >= sb[j - 1]) ? vv[j] : oz;
            ow = (d.w >= sb[j - 1]) ? vv[j] : ow;
        }
        oput[k * 256] = make_float4(ox, oy, oz, ow);
    }
}

extern "C" void kernel_launch(void* const* d_in, const int* in_sizes, int n_in,
                              void* d_out, int out_size, void* d_ws, size_t ws_size,
                              hipStream_t stream) {
    const float* x  = (const float*)d_in[0];
    const float* rp = (const float*)d_in[1];
    float* out  = (float*)d_out;
    float* ws   = (float*)d_ws;
    float* pmin = ws;                    // coop: 768 slots | fallback: 3072
    float* pmax = ws + 4096;             // disjoint in both modes

    void* args[] = {(void*)&x, (void*)&rp, (void*)&out, (void*)&pmin, (void*)&pmax};
    hipError_t err = hipLaunchCooperativeKernel((const void*)lbq_onepass,
                                                dim3(GRID_BLOCKS), dim3(256),
                                                args, 0, stream);
    if (err != hipSuccess) {
        // deterministic fallback: known-good two-kernel pipeline (R3)
        minmax_kernel<<<IMGS * 64, 256, 0, stream>>>(x, pmin, pmax);
        quant_fused<<<IMGS * 64, 256, 0, stream>>>(x, pmin, pmax, rp, out);
    }
}

// Round 14
// 108.685 us; speedup vs baseline: 1.9836x; 1.9774x over previous
//
#include <hip/hip_runtime.h>
#include <math.h>

#define IMGS 48
#define BLOCKS_A_PER_IMG 64          // 64 blk * 256 thr * 16 floats = 262144
#define BLOCKS_C_PER_IMG 32          // 32 blk * 256 thr * 32 floats = 262144

typedef float floatx4 __attribute__((ext_vector_type(4)));   // native clang vec for nt-store

__device__ __forceinline__ float vmin4(float4 a) {
    return fminf(fminf(a.x, a.y), fminf(a.z, a.w));
}
__device__ __forceinline__ float vmax4(float4 a) {
    return fmaxf(fmaxf(a.x, a.y), fmaxf(a.z, a.w));
}

// ---------------- Kernel A: per-block min/max partials ----------------
// Cold HBM read (the 268MB ws poison-fill evicts all of L3 every reset).
__global__ __launch_bounds__(256) void minmax_kernel(const float* __restrict__ x,
                                                     float* __restrict__ pmin,
                                                     float* __restrict__ pmax) {
    int blk = blockIdx.x;            // 0..3071
    int img = blk >> 6;
    int b   = blk & 63;
    const float4* xin = (const float4*)x + (size_t)img * 65536 + (size_t)b * 1024;
    int t = threadIdx.x;

    float4 a0 = xin[t];
    float4 a1 = xin[256 + t];
    float4 a2 = xin[512 + t];
    float4 a3 = xin[768 + t];
    float mn = fminf(fminf(vmin4(a0), vmin4(a1)), fminf(vmin4(a2), vmin4(a3)));
    float mx = fmaxf(fmaxf(vmax4(a0), vmax4(a1)), fmaxf(vmax4(a2), vmax4(a3)));
#pragma unroll
    for (int off = 32; off >= 1; off >>= 1) {
        mn = fminf(mn, __shfl_xor(mn, off));
        mx = fmaxf(mx, __shfl_xor(mx, off));
    }
    __shared__ float smn[4], smx[4];
    int wave = t >> 6;
    if ((t & 63) == 0) { smn[wave] = mn; smx[wave] = mx; }
    __syncthreads();
    if (t == 0) {
        pmin[blk] = fminf(fminf(smn[0], smn[1]), fminf(smn[2], smn[3]));
        pmax[blk] = fmaxf(fmaxf(smx[0], smx[1]), fmaxf(smx[2], smx[3]));
    }
}

// ------ Kernel C: fused bounds (wave 0, hidden under x loads) + quantize ------
// 8 float4/thread; all 8 loads issued before the preamble so the table build
// (final reduce + rank sort + gap values) hides under x-load latency (x is
// L3-warm after kernel A). Output via non-temporal stores (streaming, never
// re-read -> keep L2/L3 for x).
__global__ __launch_bounds__(256) void quant_fused(const float* __restrict__ x,
                                                   const float* __restrict__ pmin,
                                                   const float* __restrict__ pmax,
                                                   const float* __restrict__ rp,
                                                   float* __restrict__ out) {
    int blk  = blockIdx.x;
    int img  = blk >> 5;                 // 32 blocks/image
    int b    = blk & 31;
    int t    = threadIdx.x;
    int lane = t & 63;
    int wave = t >> 6;

    __shared__ float sorted[17];
    __shared__ float s_sb[15], s_vv[16];

    size_t base = (size_t)img * 65536 + (size_t)b * 2048 + t;
    const float4* xin = (const float4*)x + base;
    float4 d0 = xin[0];
    float4 d1 = xin[256];
    float4 d2 = xin[512];
    float4 d3 = xin[768];
    float4 d4 = xin[1024];
    float4 d5 = xin[1280];
    float4 d6 = xin[1536];
    float4 d7 = xin[1792];

    if (wave == 0) {
        // final min/max reduce over this image's 64 partials
        float mn = pmin[img * 64 + lane];
        float mx = pmax[img * 64 + lane];
#pragma unroll
        for (int off = 32; off >= 1; off >>= 1) {
            mn = fminf(mn, __shfl_xor(mn, off));
            mx = fmaxf(mx, __shfl_xor(mx, off));
        }
        float maxeps = __fadd_rn(mx, 1e-6f);

        // boundary per lane: lane0=min, lanes1..15=split[lane-1], lane16=max+1e-6
        float u = (lane >= 1 && lane <= 15) ? rp[img * 15 + (lane - 1)] : 0.0f;
        // split = u*(max-min)+min, explicit mul-then-add (match XLA, no FMA)
        float split = __fadd_rn(__fmul_rn(u, __fsub_rn(mx, mn)), mn);
        float bval  = (lane == 0) ? mn : (lane == 16 ? maxeps : split);

        // stable rank among lanes 0..16 (unique; ties broken by lane index)
        int rank = 0;
#pragma unroll
        for (int i = 0; i < 17; ++i) {
            float vi = __shfl(bval, i);
            rank += (vi < bval) || (vi == bval && i < lane);
        }
        if (lane < 17) sorted[rank] = bval;   // intra-wave dep via waitcnt

        // gap g covers [sorted[g], sorted[g+1]); membership constant inside a
        // gap -> evaluate first-matching original region (argmax) at sorted[g].
        float tg = sorted[lane & 15];
        float v  = __shfl(bval, 0);           // = min (no-match default)
        bool found = false;
#pragma unroll
        for (int r = 0; r < 16; ++r) {
            float Lr = __shfl(bval, r);       // L[0]=min, L[r]=split[r-1]
            float Rr = __shfl(bval, r + 1);   // R[r]=L[r+1], R[15]=maxeps
            bool c = (tg >= Lr) && (tg < Rr);
            v = (c && !found) ? Lr : v;
            found = found || c;
        }
        if (lane < 16)  s_vv[lane] = v;
        if (lane < 15)  s_sb[lane] = sorted[lane + 1];   // thresholds SB[1..15]
    }
    __syncthreads();

    float sb[15], vv[16];
#pragma unroll
    for (int k = 0; k < 15; ++k) sb[k] = s_sb[k];
#pragma unroll
    for (int k = 0; k < 16; ++k) vv[k] = s_vv[k];

    floatx4* oput = (floatx4*)out + base;
    float4 din[8] = {d0, d1, d2, d3, d4, d5, d6, d7};
#pragma unroll
    for (int k = 0; k < 8; ++k) {
        float4 d = din[k];
        float ox = vv[0], oy = vv[0], oz = vv[0], ow = vv[0];
#pragma unroll
        for (int j = 1; j < 16; ++j) {
            float s = sb[j - 1], w = vv[j];
            ox = (d.x >= s) ? w : ox;
            oy = (d.y >= s) ? w : oy;
            oz = (d.z >= s) ? w : oz;
            ow = (d.w >= s) ? w : ow;
        }
        floatx4 o;
        o.x = ox; o.y = oy; o.z = oz; o.w = ow;
        __builtin_nontemporal_store(o, &oput[k * 256]);
    }
}

extern "C" void kernel_launch(void* const* d_in, const int* in_sizes, int n_in,
                              void* d_out, int out_size, void* d_ws, size_t ws_size,
                              hipStream_t stream) {
    const float* x  = (const float*)d_in[0];
    const float* rp = (const float*)d_in[1];
    float* out  = (float*)d_out;
    float* ws   = (float*)d_ws;
    float* pmin = ws;                    // 48*64 = 3072 floats
    float* pmax = ws + 3072;             // 3072 floats

    minmax_kernel<<<IMGS * BLOCKS_A_PER_IMG, 256, 0, stream>>>(x, pmin, pmax);
    quant_fused<<<IMGS * BLOCKS_C_PER_IMG, 256, 0, stream>>>(x, pmin, pmax, rp, out);
}